// Round 15
// baseline (199.035 us; speedup 1.0000x reference)
//
#include <hip/hip_runtime.h>
#include <hip/hip_bf16.h>

// graph_structure_learner round 15: r14 + XCD col-locality. Edges bucketed by
// col-range into 8 buckets (3.2MB of bf16 rows per bucket < 4MB XCD L2);
// blocks with blockIdx%8==g process bucket g only -> col-gather + segsum
// atomics become XCD-local; fabric random-line count halves (row-gather only).
// Bucketing = 1 extra kernel (LDS histogram + atomic-append, order-free).
// w-pass compute structure identical to r14 (proven). A/B: if w-pass is flat,
// the fabric-line-rate theory is wrong and r14 is the roofline.

#define SLOPE    0.01f
#define THRESH_C 1e-4f
#define BN_EPS_C 1e-5f
#define SSTRIDE  32

typedef __bf16 bf16x8 __attribute__((ext_vector_type(8)));
typedef __bf16 bf16x2 __attribute__((ext_vector_type(2)));
typedef float  f32x4  __attribute__((ext_vector_type(4)));

__device__ __forceinline__ unsigned pk2(float a, float b) {
    union { bf16x2 v; unsigned u; } x;
    x.v[0] = (__bf16)a; x.v[1] = (__bf16)b;
    return x.u;
}
__device__ __forceinline__ float lo16(unsigned u) { return __uint_as_float(u << 16); }
__device__ __forceinline__ float hi16(unsigned u) { return __uint_as_float(u & 0xffff0000u); }

// ---------------- prep: zero stats/segsum/bucket counters, cvt n_feat ----------------
__global__ void prep_kernel(const float* __restrict__ nf, unsigned* __restrict__ nfb,
                            double* g_sum, double* g_sq, float* s, int* bcnt,
                            int n_nodes, int tn8) {
    int idx = blockIdx.x * blockDim.x + threadIdx.x;
    if (idx < tn8) {
        const float4* p = (const float4*)nf + (size_t)idx * 2;
        float4 f0 = p[0], f1 = p[1];
        uint4 o;
        o.x = pk2(f0.x, f0.y); o.y = pk2(f0.z, f0.w);
        o.z = pk2(f1.x, f1.y); o.w = pk2(f1.z, f1.w);
        ((uint4*)nfb)[idx] = o;
    }
    if (idx < n_nodes) s[idx] = 0.f;
    if (idx < 1024)    { g_sum[idx] = 0.0; g_sq[idx] = 0.0; }
    if (idx < 128)     bcnt[idx] = 0;
}

// ---------------- bucket edges by col-range (8 buckets, order-free append) ----------------
__global__ void bucket_kernel(const int* __restrict__ row, const int* __restrict__ col,
                              const int* __restrict__ etype, int* __restrict__ bcnt,
                              int4* __restrict__ recs, int E, int nper, int cap) {
    __shared__ int hist[8], base[8], off[8];
    const int tid = threadIdx.x;
    if (tid < 8) { hist[tid] = 0; off[tid] = 0; }
    __syncthreads();
    const int chunk = (E + gridDim.x - 1) / gridDim.x;
    const int s = blockIdx.x * chunk;
    const int e_end = (s + chunk < E) ? s + chunk : E;
    for (int e = s + tid; e < e_end; e += blockDim.x)
        atomicAdd(&hist[col[e] / nper], 1);
    __syncthreads();
    if (tid < 8) base[tid] = atomicAdd(&bcnt[tid * 16], hist[tid]);   // 64B-padded counters
    __syncthreads();
    for (int e = s + tid; e < e_end; e += blockDim.x) {
        int c = col[e];
        int g = c / nper;
        int p = base[g] + atomicAdd(&off[g], 1);
        recs[(size_t)g * cap + p] = make_int4(row[e], c, etype[e], e);
    }
}

// ---------------- stats finalize ----------------
__global__ void stats_kernel(const double* __restrict__ g_sum, const double* __restrict__ g_sq,
                             const float* __restrict__ gamma, const float* __restrict__ beta,
                             float* __restrict__ AB, int count) {
    int j = threadIdx.x;
    if (j < 128) {
        double s = 0.0, q = 0.0;
#pragma unroll
        for (int r = 0; r < 8; r++) { s += g_sum[r * 128 + j]; q += g_sq[r * 128 + j]; }
        double mu  = s / (double)count;
        double var = q / (double)count - mu * mu;
        double rstd = 1.0 / sqrt(var + (double)BN_EPS_C);
        float A = (float)rstd * gamma[j];
        AB[j]       = A;
        AB[128 + j] = beta[j] - (float)mu * A;
    }
}

// WPASS=0: BN stats over sampled edges (estride). WPASS=1: w-pass (exp+segsum).
// BF16G: bf16-table gather. BUCK: tiles come from col-bucketed records
// (blockIdx%8 selects bucket -> XCD-local col traffic).
template <int WPASS, int BF16G, int BUCK>
__global__ __launch_bounds__(256, 4) void pass_kernel(
    const float* __restrict__ n_feat, const unsigned short* __restrict__ nfb,
    const float* __restrict__ W0,
    const float* __restrict__ rel, const float* __restrict__ b0,
    const int* __restrict__ row, const int* __restrict__ col,
    const int* __restrict__ etype, const float* __restrict__ AB,
    const float* __restrict__ W1, const float* __restrict__ b1,
    double* __restrict__ g_sum, double* __restrict__ g_sq,
    float* __restrict__ segsum, float* __restrict__ out_e,
    const int4* __restrict__ recs, const int* __restrict__ bcnt, int cap,
    int E, int ntiles, int estride)
{
    __shared__ __align__(16) char lds[25600];   // A-tile 24576 B + wsum 1024 B

    const int tid  = threadIdx.x;
    const int lane = tid & 63;
    const int wv   = tid >> 6;
    const int grp  = lane >> 4;
    const int l15  = lane & 15;

    // ---- B fragments straight from global W0 ----
    bf16x8 bf[2][5];
#pragma unroll
    for (int ct = 0; ct < 2; ct++) {
        const int bcol = wv * 32 + ct * 16 + l15;
#pragma unroll
        for (int ks = 0; ks < 5; ks++) {
            const int k0 = ks * 32 + grp * 8;
#pragma unroll
            for (int j = 0; j < 8; j++)
                bf[ct][ks][j] = (__bf16)W0[(size_t)(k0 + j) * 128 + bcol];
        }
    }

    float b0v[2], A0v[2] = {0, 0}, B0v[2] = {0, 0}, W1v[2] = {0, 0}, b1v = 0.f;
#pragma unroll
    for (int ct = 0; ct < 2; ct++) {
        int c = wv * 32 + ct * 16 + l15;
        b0v[ct] = b0[c];
        if (WPASS) { A0v[ct] = AB[c]; B0v[ct] = AB[128 + c]; W1v[ct] = W1[c]; }
    }
    if (WPASS) b1v = b1[0];

    float sums[2] = {0, 0}, sqs[2] = {0, 0};

    char*  Ab   = lds;                        // 64 rows x 384 B
    float* wsum = (float*)(lds + 24576);      // [4][64]

    const float4* nf4 = (const float4*)n_feat;
    const int e_loc = tid >> 2, q = tid & 3;
    char* wr_base = Ab + e_loc * 384;
    const unsigned sw = (unsigned)(e_loc & 7) << 4;

    // bucket-mode loop bounds
    const int g   = BUCK ? (blockIdx.x & 7) : 0;
    const int bn  = BUCK ? bcnt[g * 16] : 0;
    const int4* myrec = BUCK ? (recs + (size_t)g * cap) : recs;
    const int tN    = BUCK ? ((bn + 63) >> 6) : ntiles;
    const int tBeg  = BUCK ? (blockIdx.x >> 3) : blockIdx.x;
    const int tStep = BUCK ? (gridDim.x >> 3) : gridDim.x;

    int prev_t = 0; bool have_prev = false;

    for (int t = tBeg; t < tN; t += tStep) {
        const int ebase = t << 6;

        // -------- stage: sim=exp(-|src-dst|) + rel, bf16, swizzled --------
        {
            int r = 0, c = 0, ty = 0; bool vld;
            if (BUCK) {
                const int idx = ebase + e_loc;
                vld = idx < bn;
                if (vld) { int4 rc = myrec[idx]; r = rc.x; c = rc.y; ty = rc.z; }
            } else {
                const int eid = (ebase + e_loc) * estride;
                vld = eid < E;
                if (vld) { r = row[eid]; c = col[eid]; ty = etype[eid]; }
            }
            unsigned simw[16], relw[4];
            if (vld) {
                if (BF16G) {
                    const uint4* pa = (const uint4*)(nfb + ((size_t)r << 7)) + q * 4;
                    const uint4* pb = (const uint4*)(nfb + ((size_t)c << 7)) + q * 4;
#pragma unroll
                    for (int i = 0; i < 4; i++) {
                        uint4 ua = pa[i], ub = pb[i];
                        unsigned aw[4] = {ua.x, ua.y, ua.z, ua.w};
                        unsigned bw[4] = {ub.x, ub.y, ub.z, ub.w};
#pragma unroll
                        for (int j = 0; j < 4; j++) {
                            float d0 = lo16(aw[j]) - lo16(bw[j]);
                            float d1 = hi16(aw[j]) - hi16(bw[j]);
                            simw[i * 4 + j] = pk2(__expf(-fabsf(d0)), __expf(-fabsf(d1)));
                        }
                    }
                } else {
                    const float4* ra = nf4 + (size_t)r * 32 + q * 8;
                    const float4* rb = nf4 + (size_t)c * 32 + q * 8;
#pragma unroll
                    for (int i = 0; i < 8; i++) {
                        float4 a = ra[i], b = rb[i];
                        simw[2 * i]     = pk2(__expf(-fabsf(a.x - b.x)), __expf(-fabsf(a.y - b.y)));
                        simw[2 * i + 1] = pk2(__expf(-fabsf(a.z - b.z)), __expf(-fabsf(a.w - b.w)));
                    }
                }
                const float4* rr = (const float4*)(rel + (size_t)ty * 32 + q * 8);
                float4 r0 = rr[0], r1 = rr[1];
                relw[0] = pk2(r0.x, r0.y); relw[1] = pk2(r0.z, r0.w);
                relw[2] = pk2(r1.x, r1.y); relw[3] = pk2(r1.z, r1.w);
            } else {
#pragma unroll
                for (int i = 0; i < 16; i++) simw[i] = 0u;
                relw[0] = relw[1] = relw[2] = relw[3] = 0u;
            }
#pragma unroll
            for (int wq = 0; wq < 4; wq++)
                *(uint4*)(wr_base + (((unsigned)(q * 64 + wq * 16)) ^ sw)) =
                    make_uint4(simw[4 * wq], simw[4 * wq + 1], simw[4 * wq + 2], simw[4 * wq + 3]);
            *(uint4*)(wr_base + (((unsigned)(256 + q * 16)) ^ sw)) =
                make_uint4(relw[0], relw[1], relw[2], relw[3]);
        }

        // previous tile's per-wave partials -> w -> exp -> segsum
        if (WPASS && have_prev && tid < 64) {
            int idx = (prev_t << 6) + tid;
            int e = -1, cc = 0;
            if (BUCK) {
                if (idx < bn) { int4 rc = myrec[idx]; e = rc.w; cc = rc.y; }
            } else {
                if (idx < E) { e = idx; cc = col[idx]; }
            }
            if (e >= 0) {
                float w = wsum[tid] + wsum[64 + tid] + wsum[128 + tid] + wsum[192 + tid] + b1v;
                float ev = __expf(w);
                out_e[e] = ev;
                atomicAdd(&segsum[cc], ev);
            }
        }
        __syncthreads();

        // -------- compute: h = [sim|rel] @ W0 + b0 via MFMA --------
        f32x4 acc[4][2];
#pragma unroll
        for (int rt = 0; rt < 4; rt++)
#pragma unroll
            for (int ct = 0; ct < 2; ct++)
                acc[rt][ct] = {b0v[ct], b0v[ct], b0v[ct], b0v[ct]};

#pragma unroll
        for (int rt = 0; rt < 4; rt++) {
            const int arow = rt * 16 + l15;
            const char* rbp = Ab + arow * 384;
            const unsigned asw = (unsigned)(arow & 7) << 4;
            bf16x8 a[5];
#pragma unroll
            for (int ks = 0; ks < 5; ks++)
                a[ks] = *(const bf16x8*)(rbp + (((unsigned)(ks * 64 + grp * 16)) ^ asw));
#pragma unroll
            for (int ct = 0; ct < 2; ct++)
#pragma unroll
                for (int ks = 0; ks < 5; ks++)
                    acc[rt][ct] = __builtin_amdgcn_mfma_f32_16x16x32_bf16(
                        a[ks], bf[ct][ks], acc[rt][ct], 0, 0, 0);
        }

        if (!WPASS) {
            if ((ebase + 64) * estride <= E) {
#pragma unroll
                for (int rt = 0; rt < 4; rt++)
#pragma unroll
                    for (int ct = 0; ct < 2; ct++) {
                        f32x4 h = acc[rt][ct];
#pragma unroll
                        for (int rg = 0; rg < 4; rg++) {
                            sums[ct] += h[rg];
                            sqs[ct]  = fmaf(h[rg], h[rg], sqs[ct]);
                        }
                    }
            } else {
#pragma unroll
                for (int rt = 0; rt < 4; rt++)
#pragma unroll
                    for (int rg = 0; rg < 4; rg++) {
                        int eid = (ebase + rt * 16 + grp * 4 + rg) * estride;
                        float m = (eid < E) ? 1.f : 0.f;
#pragma unroll
                        for (int ct = 0; ct < 2; ct++) {
                            float h = acc[rt][ct][rg] * m;
                            sums[ct] += h;
                            sqs[ct]  = fmaf(h, h, sqs[ct]);
                        }
                    }
            }
        } else {
#pragma unroll
            for (int rt = 0; rt < 4; rt++) {
#pragma unroll
                for (int rg = 0; rg < 4; rg++) {
                    float v = 0.f;
#pragma unroll
                    for (int ct = 0; ct < 2; ct++) {
                        float h = fmaf(acc[rt][ct][rg], A0v[ct], B0v[ct]);
                        h = h >= 0.f ? h : SLOPE * h;
                        v = fmaf(h, W1v[ct], v);
                    }
                    v += __shfl_xor(v, 1); v += __shfl_xor(v, 2);
                    v += __shfl_xor(v, 4); v += __shfl_xor(v, 8);
                    if (l15 == 0) wsum[wv * 64 + rt * 16 + grp * 4 + rg] = v;
                }
            }
            prev_t = t; have_prev = true;
        }
        __syncthreads();
    }

    if (WPASS && have_prev && tid < 64) {
        int idx = (prev_t << 6) + tid;
        int e = -1, cc = 0;
        if (BUCK) {
            if (idx < bn) { int4 rc = myrec[idx]; e = rc.w; cc = rc.y; }
        } else {
            if (idx < E) { e = idx; cc = col[idx]; }
        }
        if (e >= 0) {
            float w = wsum[tid] + wsum[64 + tid] + wsum[128 + tid] + wsum[192 + tid] + b1v;
            float ev = __expf(w);
            out_e[e] = ev;
            atomicAdd(&segsum[cc], ev);
        }
    }

    if (!WPASS) {
#pragma unroll
        for (int ct = 0; ct < 2; ct++) {
            sums[ct] += __shfl_xor(sums[ct], 16); sums[ct] += __shfl_xor(sums[ct], 32);
            sqs[ct]  += __shfl_xor(sqs[ct], 16);  sqs[ct]  += __shfl_xor(sqs[ct], 32);
        }
        if (lane < 16) {
            int rep = blockIdx.x & 7;
#pragma unroll
            for (int ct = 0; ct < 2; ct++) {
                int c = wv * 32 + ct * 16 + lane;
                atomicAdd(&g_sum[rep * 128 + c], (double)sums[ct]);
                atomicAdd(&g_sq[rep * 128 + c], (double)sqs[ct]);
            }
        }
    }
}

// ---------------- ori post-fix: e' = e^0.5 * sqrt(e) ----------------
__global__ void orifix_kernel(const int* __restrict__ ori, const int* __restrict__ col,
                              float* __restrict__ out_e, float* __restrict__ segsum, int n_ori) {
    int i = blockIdx.x * blockDim.x + threadIdx.x;
    if (i < n_ori) {
        int e = ori[i];
        float old = out_e[e];
        float ne  = 1.6487212707f * __fsqrt_rn(old);
        out_e[e] = ne;
        atomicAdd(&segsum[col[e]], ne - old);
    }
}

// ---------------- normalize + threshold ----------------
__global__ void norm_kernel(const int* __restrict__ col, const float* __restrict__ s,
                            float* __restrict__ out, int E) {
    int i = blockIdx.x * blockDim.x + threadIdx.x;
    if (i < E) {
        float v = out[i] / s[col[i]];
        out[i] = v > THRESH_C ? v : 0.f;
    }
}

extern "C" void kernel_launch(void* const* d_in, const int* in_sizes, int n_in,
                              void* d_out, int out_size, void* d_ws, size_t ws_size,
                              hipStream_t stream) {
    const float* n_feat = (const float*)d_in[0];
    const float* rel    = (const float*)d_in[1];
    const float* W0     = (const float*)d_in[2];
    const float* b0     = (const float*)d_in[3];
    const float* gamma  = (const float*)d_in[4];
    const float* beta   = (const float*)d_in[5];
    const float* W1     = (const float*)d_in[6];
    const float* b1     = (const float*)d_in[7];
    const int*   row    = (const int*)d_in[8];
    const int*   col    = (const int*)d_in[9];
    const int*   etype  = (const int*)d_in[10];
    const int*   ori    = (const int*)d_in[11];

    const int E      = in_sizes[8];
    const int nfTot  = in_sizes[0];
    const int Nn     = nfTot / 128;
    const int nOri   = in_sizes[11];
    const int ntiles = (E + 63) >> 6;
    const int nper   = (Nn + 7) / 8;
    const int cap    = E / 8 + 8192;
    float* out = (float*)d_out;

    char* ws = (char*)d_ws;
    double*   g_sum = (double*)(ws + 0);          // 8 x 128 doubles
    double*   g_sq  = (double*)(ws + 8192);
    float*    AB    = (float*)(ws + 16384);       // 256 f32
    int*      bcnt  = (int*)(ws + 17408);         // 8 counters, 64B-padded
    float*    sbuf  = (float*)(ws + 17920);       // Nn f32 (segsum)
    size_t    off_n = (17920 + 4 * (size_t)Nn + 255) & ~(size_t)255;
    unsigned short* nfb = (unsigned short*)(ws + off_n);
    size_t    off_r = (off_n + 2 * (size_t)nfTot + 255) & ~(size_t)255;
    int4*     recs  = (int4*)(ws + off_r);
    const bool fast = ws_size >= off_r + 16 * (size_t)8 * cap;

    const int tn8 = fast ? nfTot / 8 : 0;
    int prep_items = tn8 > Nn ? tn8 : Nn;
    if (prep_items < 1024) prep_items = 1024;
    prep_kernel<<<(prep_items + 255) / 256, 256, 0, stream>>>(
        n_feat, (unsigned*)nfb, g_sum, g_sq, sbuf, bcnt, Nn, tn8);

    int grid_p = ntiles < 2048 ? ntiles : 2048;
    grid_p = (grid_p + 7) & ~7;                   // multiple of 8 for bucket mode

    if (fast) {
        bucket_kernel<<<1024, 256, 0, stream>>>(row, col, etype, bcnt, recs, E, nper, cap);

        const int nS  = (E + SSTRIDE - 1) / SSTRIDE;
        const int ntS = (nS + 63) >> 6;
        const int gS  = ntS < 2048 ? ntS : 2048;
        pass_kernel<0, 1, 0><<<gS, 256, 0, stream>>>(n_feat, nfb, W0, rel, b0, row, col, etype,
                                                     AB, W1, b1, g_sum, g_sq, sbuf, out,
                                                     recs, bcnt, cap, E, ntS, SSTRIDE);
        stats_kernel<<<1, 128, 0, stream>>>(g_sum, g_sq, gamma, beta, AB, nS);

        pass_kernel<1, 1, 1><<<grid_p, 256, 0, stream>>>(n_feat, nfb, W0, rel, b0, row, col, etype,
                                                         AB, W1, b1, g_sum, g_sq, sbuf, out,
                                                         recs, bcnt, cap, E, ntiles, 1);
    } else {
        pass_kernel<0, 0, 0><<<grid_p, 256, 0, stream>>>(n_feat, nfb, W0, rel, b0, row, col, etype,
                                                         AB, W1, b1, g_sum, g_sq, sbuf, out,
                                                         recs, bcnt, cap, E, ntiles, 1);
        stats_kernel<<<1, 128, 0, stream>>>(g_sum, g_sq, gamma, beta, AB, E);
        pass_kernel<1, 0, 0><<<grid_p, 256, 0, stream>>>(n_feat, nfb, W0, rel, b0, row, col, etype,
                                                         AB, W1, b1, g_sum, g_sq, sbuf, out,
                                                         recs, bcnt, cap, E, ntiles, 1);
    }

    int nbO = (nOri + 255) / 256;
    orifix_kernel<<<nbO, 256, 0, stream>>>(ori, col, out, sbuf, nOri);

    int nbE = (E + 255) / 256;
    norm_kernel<<<nbE, 256, 0, stream>>>(col, sbuf, out, E);
}

// Round 16
// 198.741 us; speedup vs baseline: 1.0015x; 1.0015x over previous
//
#include <hip/hip_runtime.h>
#include <hip/hip_bf16.h>

// graph_structure_learner round 15: r14 + XCD col-locality. Edges bucketed by
// col-range into 8 buckets (3.2MB of bf16 rows per bucket < 4MB XCD L2);
// blocks with blockIdx%8==g process bucket g only -> col-gather + segsum
// atomics become XCD-local; fabric random-line count halves (row-gather only).
// Bucketing = 1 extra kernel (LDS histogram + atomic-append, order-free).
// w-pass compute structure identical to r14 (proven). A/B: if w-pass is flat,
// the fabric-line-rate theory is wrong and r14 is the roofline.

#define SLOPE    0.01f
#define THRESH_C 1e-4f
#define BN_EPS_C 1e-5f
#define SSTRIDE  32

typedef __bf16 bf16x8 __attribute__((ext_vector_type(8)));
typedef __bf16 bf16x2 __attribute__((ext_vector_type(2)));
typedef float  f32x4  __attribute__((ext_vector_type(4)));

__device__ __forceinline__ unsigned pk2(float a, float b) {
    union { bf16x2 v; unsigned u; } x;
    x.v[0] = (__bf16)a; x.v[1] = (__bf16)b;
    return x.u;
}
__device__ __forceinline__ float lo16(unsigned u) { return __uint_as_float(u << 16); }
__device__ __forceinline__ float hi16(unsigned u) { return __uint_as_float(u & 0xffff0000u); }

// ---------------- prep: zero stats/segsum/bucket counters, cvt n_feat ----------------
__global__ void prep_kernel(const float* __restrict__ nf, unsigned* __restrict__ nfb,
                            double* g_sum, double* g_sq, float* s, int* bcnt,
                            int n_nodes, int tn8) {
    int idx = blockIdx.x * blockDim.x + threadIdx.x;
    if (idx < tn8) {
        const float4* p = (const float4*)nf + (size_t)idx * 2;
        float4 f0 = p[0], f1 = p[1];
        uint4 o;
        o.x = pk2(f0.x, f0.y); o.y = pk2(f0.z, f0.w);
        o.z = pk2(f1.x, f1.y); o.w = pk2(f1.z, f1.w);
        ((uint4*)nfb)[idx] = o;
    }
    if (idx < n_nodes) s[idx] = 0.f;
    if (idx < 1024)    { g_sum[idx] = 0.0; g_sq[idx] = 0.0; }
    if (idx < 128)     bcnt[idx] = 0;
}

// ---------------- bucket edges by col-range (8 buckets, order-free append) ----------------
__global__ void bucket_kernel(const int* __restrict__ row, const int* __restrict__ col,
                              const int* __restrict__ etype, int* __restrict__ bcnt,
                              int4* __restrict__ recs, int E, int nper, int cap) {
    __shared__ int hist[8], base[8], off[8];
    const int tid = threadIdx.x;
    if (tid < 8) { hist[tid] = 0; off[tid] = 0; }
    __syncthreads();
    const int chunk = (E + gridDim.x - 1) / gridDim.x;
    const int s = blockIdx.x * chunk;
    const int e_end = (s + chunk < E) ? s + chunk : E;
    for (int e = s + tid; e < e_end; e += blockDim.x)
        atomicAdd(&hist[col[e] / nper], 1);
    __syncthreads();
    if (tid < 8) base[tid] = atomicAdd(&bcnt[tid * 16], hist[tid]);   // 64B-padded counters
    __syncthreads();
    for (int e = s + tid; e < e_end; e += blockDim.x) {
        int c = col[e];
        int g = c / nper;
        int p = base[g] + atomicAdd(&off[g], 1);
        recs[(size_t)g * cap + p] = make_int4(row[e], c, etype[e], e);
    }
}

// ---------------- stats finalize ----------------
__global__ void stats_kernel(const double* __restrict__ g_sum, const double* __restrict__ g_sq,
                             const float* __restrict__ gamma, const float* __restrict__ beta,
                             float* __restrict__ AB, int count) {
    int j = threadIdx.x;
    if (j < 128) {
        double s = 0.0, q = 0.0;
#pragma unroll
        for (int r = 0; r < 8; r++) { s += g_sum[r * 128 + j]; q += g_sq[r * 128 + j]; }
        double mu  = s / (double)count;
        double var = q / (double)count - mu * mu;
        double rstd = 1.0 / sqrt(var + (double)BN_EPS_C);
        float A = (float)rstd * gamma[j];
        AB[j]       = A;
        AB[128 + j] = beta[j] - (float)mu * A;
    }
}

// WPASS=0: BN stats over sampled edges (estride). WPASS=1: w-pass (exp+segsum).
// BF16G: bf16-table gather. BUCK: tiles come from col-bucketed records
// (blockIdx%8 selects bucket -> XCD-local col traffic).
template <int WPASS, int BF16G, int BUCK>
__global__ __launch_bounds__(256, 4) void pass_kernel(
    const float* __restrict__ n_feat, const unsigned short* __restrict__ nfb,
    const float* __restrict__ W0,
    const float* __restrict__ rel, const float* __restrict__ b0,
    const int* __restrict__ row, const int* __restrict__ col,
    const int* __restrict__ etype, const float* __restrict__ AB,
    const float* __restrict__ W1, const float* __restrict__ b1,
    double* __restrict__ g_sum, double* __restrict__ g_sq,
    float* __restrict__ segsum, float* __restrict__ out_e,
    const int4* __restrict__ recs, const int* __restrict__ bcnt, int cap,
    int E, int ntiles, int estride)
{
    __shared__ __align__(16) char lds[25600];   // A-tile 24576 B + wsum 1024 B

    const int tid  = threadIdx.x;
    const int lane = tid & 63;
    const int wv   = tid >> 6;
    const int grp  = lane >> 4;
    const int l15  = lane & 15;

    // ---- B fragments straight from global W0 ----
    bf16x8 bf[2][5];
#pragma unroll
    for (int ct = 0; ct < 2; ct++) {
        const int bcol = wv * 32 + ct * 16 + l15;
#pragma unroll
        for (int ks = 0; ks < 5; ks++) {
            const int k0 = ks * 32 + grp * 8;
#pragma unroll
            for (int j = 0; j < 8; j++)
                bf[ct][ks][j] = (__bf16)W0[(size_t)(k0 + j) * 128 + bcol];
        }
    }

    float b0v[2], A0v[2] = {0, 0}, B0v[2] = {0, 0}, W1v[2] = {0, 0}, b1v = 0.f;
#pragma unroll
    for (int ct = 0; ct < 2; ct++) {
        int c = wv * 32 + ct * 16 + l15;
        b0v[ct] = b0[c];
        if (WPASS) { A0v[ct] = AB[c]; B0v[ct] = AB[128 + c]; W1v[ct] = W1[c]; }
    }
    if (WPASS) b1v = b1[0];

    float sums[2] = {0, 0}, sqs[2] = {0, 0};

    char*  Ab   = lds;                        // 64 rows x 384 B
    float* wsum = (float*)(lds + 24576);      // [4][64]

    const float4* nf4 = (const float4*)n_feat;
    const int e_loc = tid >> 2, q = tid & 3;
    char* wr_base = Ab + e_loc * 384;
    const unsigned sw = (unsigned)(e_loc & 7) << 4;

    // bucket-mode loop bounds
    const int g   = BUCK ? (blockIdx.x & 7) : 0;
    const int bn  = BUCK ? bcnt[g * 16] : 0;
    const int4* myrec = BUCK ? (recs + (size_t)g * cap) : recs;
    const int tN    = BUCK ? ((bn + 63) >> 6) : ntiles;
    const int tBeg  = BUCK ? (blockIdx.x >> 3) : blockIdx.x;
    const int tStep = BUCK ? (gridDim.x >> 3) : gridDim.x;

    int prev_t = 0; bool have_prev = false;

    for (int t = tBeg; t < tN; t += tStep) {
        const int ebase = t << 6;

        // -------- stage: sim=exp(-|src-dst|) + rel, bf16, swizzled --------
        {
            int r = 0, c = 0, ty = 0; bool vld;
            if (BUCK) {
                const int idx = ebase + e_loc;
                vld = idx < bn;
                if (vld) { int4 rc = myrec[idx]; r = rc.x; c = rc.y; ty = rc.z; }
            } else {
                const int eid = (ebase + e_loc) * estride;
                vld = eid < E;
                if (vld) { r = row[eid]; c = col[eid]; ty = etype[eid]; }
            }
            unsigned simw[16], relw[4];
            if (vld) {
                if (BF16G) {
                    const uint4* pa = (const uint4*)(nfb + ((size_t)r << 7)) + q * 4;
                    const uint4* pb = (const uint4*)(nfb + ((size_t)c << 7)) + q * 4;
#pragma unroll
                    for (int i = 0; i < 4; i++) {
                        uint4 ua = pa[i], ub = pb[i];
                        unsigned aw[4] = {ua.x, ua.y, ua.z, ua.w};
                        unsigned bw[4] = {ub.x, ub.y, ub.z, ub.w};
#pragma unroll
                        for (int j = 0; j < 4; j++) {
                            float d0 = lo16(aw[j]) - lo16(bw[j]);
                            float d1 = hi16(aw[j]) - hi16(bw[j]);
                            simw[i * 4 + j] = pk2(__expf(-fabsf(d0)), __expf(-fabsf(d1)));
                        }
                    }
                } else {
                    const float4* ra = nf4 + (size_t)r * 32 + q * 8;
                    const float4* rb = nf4 + (size_t)c * 32 + q * 8;
#pragma unroll
                    for (int i = 0; i < 8; i++) {
                        float4 a = ra[i], b = rb[i];
                        simw[2 * i]     = pk2(__expf(-fabsf(a.x - b.x)), __expf(-fabsf(a.y - b.y)));
                        simw[2 * i + 1] = pk2(__expf(-fabsf(a.z - b.z)), __expf(-fabsf(a.w - b.w)));
                    }
                }
                const float4* rr = (const float4*)(rel + (size_t)ty * 32 + q * 8);
                float4 r0 = rr[0], r1 = rr[1];
                relw[0] = pk2(r0.x, r0.y); relw[1] = pk2(r0.z, r0.w);
                relw[2] = pk2(r1.x, r1.y); relw[3] = pk2(r1.z, r1.w);
            } else {
#pragma unroll
                for (int i = 0; i < 16; i++) simw[i] = 0u;
                relw[0] = relw[1] = relw[2] = relw[3] = 0u;
            }
#pragma unroll
            for (int wq = 0; wq < 4; wq++)
                *(uint4*)(wr_base + (((unsigned)(q * 64 + wq * 16)) ^ sw)) =
                    make_uint4(simw[4 * wq], simw[4 * wq + 1], simw[4 * wq + 2], simw[4 * wq + 3]);
            *(uint4*)(wr_base + (((unsigned)(256 + q * 16)) ^ sw)) =
                make_uint4(relw[0], relw[1], relw[2], relw[3]);
        }

        // previous tile's per-wave partials -> w -> exp -> segsum
        if (WPASS && have_prev && tid < 64) {
            int idx = (prev_t << 6) + tid;
            int e = -1, cc = 0;
            if (BUCK) {
                if (idx < bn) { int4 rc = myrec[idx]; e = rc.w; cc = rc.y; }
            } else {
                if (idx < E) { e = idx; cc = col[idx]; }
            }
            if (e >= 0) {
                float w = wsum[tid] + wsum[64 + tid] + wsum[128 + tid] + wsum[192 + tid] + b1v;
                float ev = __expf(w);
                out_e[e] = ev;
                atomicAdd(&segsum[cc], ev);
            }
        }
        __syncthreads();

        // -------- compute: h = [sim|rel] @ W0 + b0 via MFMA --------
        f32x4 acc[4][2];
#pragma unroll
        for (int rt = 0; rt < 4; rt++)
#pragma unroll
            for (int ct = 0; ct < 2; ct++)
                acc[rt][ct] = {b0v[ct], b0v[ct], b0v[ct], b0v[ct]};

#pragma unroll
        for (int rt = 0; rt < 4; rt++) {
            const int arow = rt * 16 + l15;
            const char* rbp = Ab + arow * 384;
            const unsigned asw = (unsigned)(arow & 7) << 4;
            bf16x8 a[5];
#pragma unroll
            for (int ks = 0; ks < 5; ks++)
                a[ks] = *(const bf16x8*)(rbp + (((unsigned)(ks * 64 + grp * 16)) ^ asw));
#pragma unroll
            for (int ct = 0; ct < 2; ct++)
#pragma unroll
                for (int ks = 0; ks < 5; ks++)
                    acc[rt][ct] = __builtin_amdgcn_mfma_f32_16x16x32_bf16(
                        a[ks], bf[ct][ks], acc[rt][ct], 0, 0, 0);
        }

        if (!WPASS) {
            if ((ebase + 64) * estride <= E) {
#pragma unroll
                for (int rt = 0; rt < 4; rt++)
#pragma unroll
                    for (int ct = 0; ct < 2; ct++) {
                        f32x4 h = acc[rt][ct];
#pragma unroll
                        for (int rg = 0; rg < 4; rg++) {
                            sums[ct] += h[rg];
                            sqs[ct]  = fmaf(h[rg], h[rg], sqs[ct]);
                        }
                    }
            } else {
#pragma unroll
                for (int rt = 0; rt < 4; rt++)
#pragma unroll
                    for (int rg = 0; rg < 4; rg++) {
                        int eid = (ebase + rt * 16 + grp * 4 + rg) * estride;
                        float m = (eid < E) ? 1.f : 0.f;
#pragma unroll
                        for (int ct = 0; ct < 2; ct++) {
                            float h = acc[rt][ct][rg] * m;
                            sums[ct] += h;
                            sqs[ct]  = fmaf(h, h, sqs[ct]);
                        }
                    }
            }
        } else {
#pragma unroll
            for (int rt = 0; rt < 4; rt++) {
#pragma unroll
                for (int rg = 0; rg < 4; rg++) {
                    float v = 0.f;
#pragma unroll
                    for (int ct = 0; ct < 2; ct++) {
                        float h = fmaf(acc[rt][ct][rg], A0v[ct], B0v[ct]);
                        h = h >= 0.f ? h : SLOPE * h;
                        v = fmaf(h, W1v[ct], v);
                    }
                    v += __shfl_xor(v, 1); v += __shfl_xor(v, 2);
                    v += __shfl_xor(v, 4); v += __shfl_xor(v, 8);
                    if (l15 == 0) wsum[wv * 64 + rt * 16 + grp * 4 + rg] = v;
                }
            }
            prev_t = t; have_prev = true;
        }
        __syncthreads();
    }

    if (WPASS && have_prev && tid < 64) {
        int idx = (prev_t << 6) + tid;
        int e = -1, cc = 0;
        if (BUCK) {
            if (idx < bn) { int4 rc = myrec[idx]; e = rc.w; cc = rc.y; }
        } else {
            if (idx < E) { e = idx; cc = col[idx]; }
        }
        if (e >= 0) {
            float w = wsum[tid] + wsum[64 + tid] + wsum[128 + tid] + wsum[192 + tid] + b1v;
            float ev = __expf(w);
            out_e[e] = ev;
            atomicAdd(&segsum[cc], ev);
        }
    }

    if (!WPASS) {
#pragma unroll
        for (int ct = 0; ct < 2; ct++) {
            sums[ct] += __shfl_xor(sums[ct], 16); sums[ct] += __shfl_xor(sums[ct], 32);
            sqs[ct]  += __shfl_xor(sqs[ct], 16);  sqs[ct]  += __shfl_xor(sqs[ct], 32);
        }
        if (lane < 16) {
            int rep = blockIdx.x & 7;
#pragma unroll
            for (int ct = 0; ct < 2; ct++) {
                int c = wv * 32 + ct * 16 + lane;
                atomicAdd(&g_sum[rep * 128 + c], (double)sums[ct]);
                atomicAdd(&g_sq[rep * 128 + c], (double)sqs[ct]);
            }
        }
    }
}

// ---------------- ori post-fix: e' = e^0.5 * sqrt(e) ----------------
__global__ void orifix_kernel(const int* __restrict__ ori, const int* __restrict__ col,
                              float* __restrict__ out_e, float* __restrict__ segsum, int n_ori) {
    int i = blockIdx.x * blockDim.x + threadIdx.x;
    if (i < n_ori) {
        int e = ori[i];
        float old = out_e[e];
        float ne  = 1.6487212707f * __fsqrt_rn(old);
        out_e[e] = ne;
        atomicAdd(&segsum[col[e]], ne - old);
    }
}

// ---------------- normalize + threshold ----------------
__global__ void norm_kernel(const int* __restrict__ col, const float* __restrict__ s,
                            float* __restrict__ out, int E) {
    int i = blockIdx.x * blockDim.x + threadIdx.x;
    if (i < E) {
        float v = out[i] / s[col[i]];
        out[i] = v > THRESH_C ? v : 0.f;
    }
}

extern "C" void kernel_launch(void* const* d_in, const int* in_sizes, int n_in,
                              void* d_out, int out_size, void* d_ws, size_t ws_size,
                              hipStream_t stream) {
    const float* n_feat = (const float*)d_in[0];
    const float* rel    = (const float*)d_in[1];
    const float* W0     = (const float*)d_in[2];
    const float* b0     = (const float*)d_in[3];
    const float* gamma  = (const float*)d_in[4];
    const float* beta   = (const float*)d_in[5];
    const float* W1     = (const float*)d_in[6];
    const float* b1     = (const float*)d_in[7];
    const int*   row    = (const int*)d_in[8];
    const int*   col    = (const int*)d_in[9];
    const int*   etype  = (const int*)d_in[10];
    const int*   ori    = (const int*)d_in[11];

    const int E      = in_sizes[8];
    const int nfTot  = in_sizes[0];
    const int Nn     = nfTot / 128;
    const int nOri   = in_sizes[11];
    const int ntiles = (E + 63) >> 6;
    const int nper   = (Nn + 7) / 8;
    const int cap    = E / 8 + 8192;
    float* out = (float*)d_out;

    char* ws = (char*)d_ws;
    double*   g_sum = (double*)(ws + 0);          // 8 x 128 doubles
    double*   g_sq  = (double*)(ws + 8192);
    float*    AB    = (float*)(ws + 16384);       // 256 f32
    int*      bcnt  = (int*)(ws + 17408);         // 8 counters, 64B-padded
    float*    sbuf  = (float*)(ws + 17920);       // Nn f32 (segsum)
    size_t    off_n = (17920 + 4 * (size_t)Nn + 255) & ~(size_t)255;
    unsigned short* nfb = (unsigned short*)(ws + off_n);
    size_t    off_r = (off_n + 2 * (size_t)nfTot + 255) & ~(size_t)255;
    int4*     recs  = (int4*)(ws + off_r);
    const bool fast = ws_size >= off_r + 16 * (size_t)8 * cap;

    const int tn8 = fast ? nfTot / 8 : 0;
    int prep_items = tn8 > Nn ? tn8 : Nn;
    if (prep_items < 1024) prep_items = 1024;
    prep_kernel<<<(prep_items + 255) / 256, 256, 0, stream>>>(
        n_feat, (unsigned*)nfb, g_sum, g_sq, sbuf, bcnt, Nn, tn8);

    int grid_p = ntiles < 2048 ? ntiles : 2048;
    grid_p = (grid_p + 7) & ~7;                   // multiple of 8 for bucket mode

    if (fast) {
        bucket_kernel<<<1024, 256, 0, stream>>>(row, col, etype, bcnt, recs, E, nper, cap);

        const int nS  = (E + SSTRIDE - 1) / SSTRIDE;
        const int ntS = (nS + 63) >> 6;
        const int gS  = ntS < 2048 ? ntS : 2048;
        pass_kernel<0, 1, 0><<<gS, 256, 0, stream>>>(n_feat, nfb, W0, rel, b0, row, col, etype,
                                                     AB, W1, b1, g_sum, g_sq, sbuf, out,
                                                     recs, bcnt, cap, E, ntS, SSTRIDE);
        stats_kernel<<<1, 128, 0, stream>>>(g_sum, g_sq, gamma, beta, AB, nS);

        pass_kernel<1, 1, 1><<<grid_p, 256, 0, stream>>>(n_feat, nfb, W0, rel, b0, row, col, etype,
                                                         AB, W1, b1, g_sum, g_sq, sbuf, out,
                                                         recs, bcnt, cap, E, ntiles, 1);
    } else {
        pass_kernel<0, 0, 0><<<grid_p, 256, 0, stream>>>(n_feat, nfb, W0, rel, b0, row, col, etype,
                                                         AB, W1, b1, g_sum, g_sq, sbuf, out,
                                                         recs, bcnt, cap, E, ntiles, 1);
        stats_kernel<<<1, 128, 0, stream>>>(g_sum, g_sq, gamma, beta, AB, E);
        pass_kernel<1, 0, 0><<<grid_p, 256, 0, stream>>>(n_feat, nfb, W0, rel, b0, row, col, etype,
                                                         AB, W1, b1, g_sum, g_sq, sbuf, out,
                                                         recs, bcnt, cap, E, ntiles, 1);
    }

    int nbO = (nOri + 255) / 256;
    orifix_kernel<<<nbO, 256, 0, stream>>>(ori, col, out, sbuf, nOri);

    int nbE = (E + 255) / 256;
    norm_kernel<<<nbE, 256, 0, stream>>>(col, sbuf, out, E);
}